// Round 4
// baseline (125.100 us; speedup 1.0000x reference)
//
#include <hip/hip_runtime.h>
#include <cstdint>

// Problem: y[m][n] = sum_k x[m][k] * (q[n][k] * scale[n]) + bias[n]
// M=32, K=8192, N=8192; q = signed int4 nibbles packed 8 per int32.
// Working hypothesis (round 4): harness upcasts all fp16 tensors to FLOAT32
// on device (inputs AND output). b_packed stays int32.
#define M_DIM 32
#define K_DIM 8192
#define N_DIM 8192

typedef _Float16 f16x8 __attribute__((ext_vector_type(8)));
typedef float    f32x4 __attribute__((ext_vector_type(4)));

// dword (8 packed nibbles) -> 8 exact f16 in [-8,7]; element j = nibble j.
__device__ __forceinline__ f16x8 dq8(uint32_t w) {
  f16x8 r;
#pragma unroll
  for (int j = 0; j < 8; ++j) {
    int q = ((int)(w << (28 - 4 * j))) >> 28;   // sign-extended nibble
    r[j] = (_Float16)q;
  }
  return r;
}

// 8 consecutive f32 -> f16x8 (two aligned float4 loads done by caller).
__device__ __forceinline__ f16x8 cvtA8(f32x4 lo, f32x4 hi) {
  f16x8 r;
#pragma unroll
  for (int j = 0; j < 4; ++j) r[j]     = (_Float16)lo[j];
#pragma unroll
  for (int j = 0; j < 4; ++j) r[j + 4] = (_Float16)hi[j];
  return r;
}

__device__ __forceinline__ uint32_t u4e(uint4 v, int t) {
  return (t == 0) ? v.x : (t == 1) ? v.y : (t == 2) ? v.z : v.w;
}

// 256 WGs x 512 threads. WG = 32 output cols (n) x all 32 rows (m).
// 8 waves split K into 1024-wide ranges; f32 MFMA accumulate; scalar-store
// LDS cross-wave reduce; rowwise scale+bias epilogue.
//
// k-scramble note: MFMA slot (t, quad, j) receives data
// k = (c*16 + quad*4 + t)*8 + j from BOTH operands — same bijection on A and
// B, so the dot product is exact regardless of the hardware's nominal k map.
__global__ __launch_bounds__(512) void qgemm_kernel(
    const uint32_t* __restrict__ bq,     // packed int4 [N, K/8]
    const float*    __restrict__ x,      // f32 [32, 8192]
    const float*    __restrict__ sc,     // f32 [8192]
    const float*    __restrict__ bi,     // f32 [8192]
    float*          __restrict__ out) {  // f32 [32, 8192]
  __shared__ float red[8][32][40];       // [wave][n][m], stride 40 (160B rows)

  const int tid  = threadIdx.x;
  const int w    = tid >> 6;             // wave 0..7 -> k0 = w*1024
  const int lane = tid & 63;
  const int l16  = lane & 15;
  const int quad = lane >> 4;
  const int n0   = blockIdx.x << 5;      // 32 n per WG

  // B as uint4: row (n0 + nt*16 + l16), uint4 index row*256 + w*32 + c*4 + quad
  const uint4* bq4 = (const uint4*)bq;
  const uint4* bp0 = bq4 + (size_t)(n0 + l16) * 256 + (w << 5) + quad;
  const uint4* bp1 = bp0 + (size_t)16 * 256;
  // A: float offset l16*8192 + w*1024 + quad*32 + c*128 + t*8 (+4)
  const float* ap0 = x + (size_t)l16 * K_DIM + (w << 10) + (quad << 5);
  const float* ap1 = ap0 + (size_t)16 * K_DIM;

  f32x4 acc00 = {0.f, 0.f, 0.f, 0.f};
  f32x4 acc01 = {0.f, 0.f, 0.f, 0.f};
  f32x4 acc10 = {0.f, 0.f, 0.f, 0.f};
  f32x4 acc11 = {0.f, 0.f, 0.f, 0.f};

#pragma unroll
  for (int c = 0; c < 8; ++c) {          // 8 chunks x 128 k per wave
    const uint4 wb0 = bp0[c * 4];        // 4 dwords, n-tile 0
    const uint4 wb1 = bp1[c * 4];        // 4 dwords, n-tile 1
#pragma unroll
    for (int t = 0; t < 4; ++t) {
      const float* a0 = ap0 + c * 128 + t * 8;
      const float* a1 = ap1 + c * 128 + t * 8;
      f16x8 fa0 = cvtA8(*(const f32x4*)a0, *(const f32x4*)(a0 + 4));
      f16x8 fa1 = cvtA8(*(const f32x4*)a1, *(const f32x4*)(a1 + 4));
      f16x8 fb0 = dq8(u4e(wb0, t));
      f16x8 fb1 = dq8(u4e(wb1, t));
      acc00 = __builtin_amdgcn_mfma_f32_16x16x32_f16(fa0, fb0, acc00, 0, 0, 0);
      acc01 = __builtin_amdgcn_mfma_f32_16x16x32_f16(fa1, fb0, acc01, 0, 0, 0);
      acc10 = __builtin_amdgcn_mfma_f32_16x16x32_f16(fa0, fb1, acc10, 0, 0, 0);
      acc11 = __builtin_amdgcn_mfma_f32_16x16x32_f16(fa1, fb1, acc11, 0, 0, 0);
    }
  }

  // C/D layout: col(n) = lane&15, row(m) = quad*4 + reg. Scalar stores
  // (alignment-proof), one-time epilogue cost.
#pragma unroll
  for (int r = 0; r < 4; ++r) {
    const int mr = (quad << 2) + r;
    red[w][l16][mr]           = acc00[r];
    red[w][l16][mr + 16]      = acc01[r];
    red[w][l16 + 16][mr]      = acc10[r];
    red[w][l16 + 16][mr + 16] = acc11[r];
  }

  __syncthreads();

  // Cross-wave reduce + epilogue: thread t -> n = t&31, m in {t>>5, t>>5+16}
  const int n  = tid & 31;
  const int mh = tid >> 5;               // 0..15
  float s0 = 0.f, s1 = 0.f;
#pragma unroll
  for (int ww = 0; ww < 8; ++ww) {
    s0 += red[ww][n][mh];
    s1 += red[ww][n][mh + 16];
  }
  const int gn = n0 + n;
  const float scale = sc[gn];
  const float bias  = bi[gn];
  out[(size_t)mh * N_DIM + gn]        = fmaf(s0, scale, bias);
  out[(size_t)(mh + 16) * N_DIM + gn] = fmaf(s1, scale, bias);
}

extern "C" void kernel_launch(void* const* d_in, const int* in_sizes, int n_in,
                              void* d_out, int out_size, void* d_ws, size_t ws_size,
                              hipStream_t stream) {
  const float*    x  = (const float*)d_in[0];     // f32 [32,8192] (fp16 upcast)
  const uint32_t* bq = (const uint32_t*)d_in[1];  // int32 [8192,1024]
  const float*    sc = (const float*)d_in[2];     // f32 [8192]
  const float*    bi = (const float*)d_in[3];     // f32 [8192]
  float*          y  = (float*)d_out;             // f32 [32,8192]

  qgemm_kernel<<<N_DIM / 32, 512, 0, stream>>>(bq, x, sc, bi, y);
}

// Round 5
// 87.748 us; speedup vs baseline: 1.4257x; 1.4257x over previous
//
#include <hip/hip_runtime.h>
#include <cstdint>

// y[m][n] = sum_k x[m][k] * (q[n][k] * scale[n]) + bias[n]
// M=32, K=8192, N=8192; q = signed int4 nibbles packed 8 per int32.
// Harness dtype reality (verified round 4): fp16 tensors are FLOAT32 on
// device (inputs and output); b_packed is int32.
#define M_DIM 32
#define K_DIM 8192
#define N_DIM 8192

typedef _Float16 f16x8 __attribute__((ext_vector_type(8)));
typedef float    f32x4 __attribute__((ext_vector_type(4)));

// dword (8 packed nibbles) -> 8 exact f16 in [-8,7]; element j = nibble j.
__device__ __forceinline__ f16x8 dq8(uint32_t w) {
  f16x8 r;
#pragma unroll
  for (int j = 0; j < 8; ++j) {
    int q = ((int)(w << (28 - 4 * j))) >> 28;   // sign-extended nibble
    r[j] = (_Float16)q;
  }
  return r;
}

__device__ __forceinline__ uint32_t u4e(uint4 v, int t) {
  return (t == 0) ? v.x : (t == 1) ? v.y : (t == 2) ? v.z : v.w;
}

// -------- x transpose/downcast: f32 x[32][8192] -> f16 xp[g=k/8][m][8] -----
// Reads fully coalesced (32 B/thread, g fastest); writes strided 16 B (tiny
// kernel, ~0.5 MB total, negligible).
__global__ __launch_bounds__(256) void xprep_kernel(
    const float* __restrict__ x, uint4* __restrict__ xp) {
  const int T = blockIdx.x * 256 + threadIdx.x;  // 0..32767
  const int m = T >> 10;                         // 0..31
  const int g = T & 1023;                        // 0..1023
  const f32x4* p = (const f32x4*)(x + (size_t)m * K_DIM + (size_t)g * 8);
  f32x4 lo = p[0], hi = p[1];
  union { uint4 q; f16x8 v; } o;
#pragma unroll
  for (int j = 0; j < 4; ++j) {
    o.v[j]     = (_Float16)lo[j];
    o.v[j + 4] = (_Float16)hi[j];
  }
  xp[(size_t)g * 32 + m] = o.q;
}

// -------- main GEMM (xp path): 256 WGs x 1024 thr (16 waves) ---------------
// WG = 32 cols (n) x 32 rows (m); 16 waves k-split (512 k each, 4 chunks of
// 128). All 4 B-chunks prefetched up front; A double-buffered; f32 MFMA
// accumulate; LDS cross-wave reduce (stride-33, conflict-free epilogue);
// rowwise scale+bias.
// k-scramble: MFMA slot (c,t,quad,j) takes k = (w*64+c*16+quad*4+t)*8 + j
// from BOTH operands — same bijection on A and B, so the dot is exact.
__global__ __launch_bounds__(1024, 4) void qgemm_xp(
    const uint32_t* __restrict__ bq,     // packed int4 [N, K/8]
    const uint4*    __restrict__ xp,     // f16 [1024][32][8]
    const float*    __restrict__ sc,     // f32 [8192]
    const float*    __restrict__ bi,     // f32 [8192]
    float*          __restrict__ out) {  // f32 [32, 8192]
  __shared__ float red[16][32][33];      // [wave][n][m], stride 33 (66 KB)

  const int tid  = threadIdx.x;
  const int w    = tid >> 6;             // wave 0..15 -> k0 = w*512
  const int lane = tid & 63;
  const int l16  = lane & 15;
  const int quad = lane >> 4;
  const int n0   = blockIdx.x << 5;      // 32 n per WG

  // B uint4 index: row*256 + w*16 + c*4 + quad; rows n0+l16, n0+l16+16
  const uint4* bq4 = (const uint4*)bq;
  const uint4* bp0 = bq4 + (size_t)(n0 + l16) * 256 + (w << 4) + quad;
  const uint4* bp1 = bp0 + (size_t)16 * 256;
  // A uint4 index: g*32 + m; g = w*64 + c*16 + quad*4 + t; m = l16 (+16)
  const uint4* ap  = xp + (size_t)(((w << 6) + (quad << 2)) * 32 + l16);

  // Prefetch ALL B (the HBM stream): 4 chunks x 2 n-tiles = 8 outstanding.
  uint4 b0[4], b1[4];
#pragma unroll
  for (int c = 0; c < 4; ++c) { b0[c] = bp0[c * 4]; b1[c] = bp1[c * 4]; }

  // Prefetch A chunk 0 (L2-resident after first WGs).
  uint4 a[8], an[8];
#pragma unroll
  for (int t = 0; t < 4; ++t) {
    a[t]     = ap[t * 32];               // m-tile 0
    a[4 + t] = ap[t * 32 + 16];          // m-tile 1
  }

  f32x4 acc00 = {0.f, 0.f, 0.f, 0.f};
  f32x4 acc01 = {0.f, 0.f, 0.f, 0.f};
  f32x4 acc10 = {0.f, 0.f, 0.f, 0.f};
  f32x4 acc11 = {0.f, 0.f, 0.f, 0.f};

#pragma unroll
  for (int c = 0; c < 4; ++c) {          // 4 chunks x 128 k per wave
    const int cn = (c + 1) & 3;          // last iter refetches c=0 (harmless)
#pragma unroll
    for (int t = 0; t < 4; ++t) {
      an[t]     = ap[(cn * 16 + t) * 32];
      an[4 + t] = ap[(cn * 16 + t) * 32 + 16];
    }
#pragma unroll
    for (int t = 0; t < 4; ++t) {
      f16x8 fb0 = dq8(u4e(b0[c], t));
      f16x8 fb1 = dq8(u4e(b1[c], t));
      f16x8 fa0 = __builtin_bit_cast(f16x8, a[t]);
      f16x8 fa1 = __builtin_bit_cast(f16x8, a[4 + t]);
      acc00 = __builtin_amdgcn_mfma_f32_16x16x32_f16(fa0, fb0, acc00, 0, 0, 0);
      acc01 = __builtin_amdgcn_mfma_f32_16x16x32_f16(fa1, fb0, acc01, 0, 0, 0);
      acc10 = __builtin_amdgcn_mfma_f32_16x16x32_f16(fa0, fb1, acc10, 0, 0, 0);
      acc11 = __builtin_amdgcn_mfma_f32_16x16x32_f16(fa1, fb1, acc11, 0, 0, 0);
    }
#pragma unroll
    for (int i = 0; i < 8; ++i) a[i] = an[i];
  }

  // C/D layout (verified round 4): n = lane&15 (from B operand), m = quad*4+r.
#pragma unroll
  for (int r = 0; r < 4; ++r) {
    const int mr = (quad << 2) + r;
    red[w][l16][mr]           = acc00[r];
    red[w][l16][mr + 16]      = acc01[r];
    red[w][l16 + 16][mr]      = acc10[r];
    red[w][l16 + 16][mr + 16] = acc11[r];
  }

  __syncthreads();

  // 1024 threads = exactly one output each: n = tid&31, m = tid>>5.
  const int n = tid & 31;
  const int m = tid >> 5;
  float s = 0.f;
#pragma unroll
  for (int ww = 0; ww < 16; ++ww) s += red[ww][n][m];
  const int gn = n0 + n;
  out[(size_t)m * N_DIM + gn] = fmaf(s, sc[gn], bi[gn]);
}

// -------- fallback (no workspace): round-4 kernel, known-good --------------
__global__ __launch_bounds__(512) void qgemm_direct(
    const uint32_t* __restrict__ bq, const float* __restrict__ x,
    const float* __restrict__ sc, const float* __restrict__ bi,
    float* __restrict__ out) {
  __shared__ float red[8][32][40];

  const int tid  = threadIdx.x;
  const int w    = tid >> 6;
  const int lane = tid & 63;
  const int l16  = lane & 15;
  const int quad = lane >> 4;
  const int n0   = blockIdx.x << 5;

  const uint4* bq4 = (const uint4*)bq;
  const uint4* bp0 = bq4 + (size_t)(n0 + l16) * 256 + (w << 5) + quad;
  const uint4* bp1 = bp0 + (size_t)16 * 256;
  const float* ap0 = x + (size_t)l16 * K_DIM + (w << 10) + (quad << 5);
  const float* ap1 = ap0 + (size_t)16 * K_DIM;

  f32x4 acc00 = {0.f,0.f,0.f,0.f}, acc01 = {0.f,0.f,0.f,0.f};
  f32x4 acc10 = {0.f,0.f,0.f,0.f}, acc11 = {0.f,0.f,0.f,0.f};

#pragma unroll
  for (int c = 0; c < 8; ++c) {
    const uint4 wb0 = bp0[c * 4];
    const uint4 wb1 = bp1[c * 4];
#pragma unroll
    for (int t = 0; t < 4; ++t) {
      const float* a0 = ap0 + c * 128 + t * 8;
      const float* a1 = ap1 + c * 128 + t * 8;
      f32x4 l0 = *(const f32x4*)a0, h0 = *(const f32x4*)(a0 + 4);
      f32x4 l1 = *(const f32x4*)a1, h1 = *(const f32x4*)(a1 + 4);
      f16x8 fa0, fa1;
#pragma unroll
      for (int j = 0; j < 4; ++j) {
        fa0[j] = (_Float16)l0[j]; fa0[j+4] = (_Float16)h0[j];
        fa1[j] = (_Float16)l1[j]; fa1[j+4] = (_Float16)h1[j];
      }
      f16x8 fb0 = dq8(u4e(wb0, t));
      f16x8 fb1 = dq8(u4e(wb1, t));
      acc00 = __builtin_amdgcn_mfma_f32_16x16x32_f16(fa0, fb0, acc00, 0, 0, 0);
      acc01 = __builtin_amdgcn_mfma_f32_16x16x32_f16(fa1, fb0, acc01, 0, 0, 0);
      acc10 = __builtin_amdgcn_mfma_f32_16x16x32_f16(fa0, fb1, acc10, 0, 0, 0);
      acc11 = __builtin_amdgcn_mfma_f32_16x16x32_f16(fa1, fb1, acc11, 0, 0, 0);
    }
  }

#pragma unroll
  for (int r = 0; r < 4; ++r) {
    const int mr = (quad << 2) + r;
    red[w][l16][mr]           = acc00[r];
    red[w][l16][mr + 16]      = acc01[r];
    red[w][l16 + 16][mr]      = acc10[r];
    red[w][l16 + 16][mr + 16] = acc11[r];
  }
  __syncthreads();
  const int n  = tid & 31;
  const int mh = tid >> 5;
  float s0 = 0.f, s1 = 0.f;
#pragma unroll
  for (int ww = 0; ww < 8; ++ww) {
    s0 += red[ww][n][mh];
    s1 += red[ww][n][mh + 16];
  }
  const int gn = n0 + n;
  out[(size_t)mh * N_DIM + gn]        = fmaf(s0, sc[gn], bi[gn]);
  out[(size_t)(mh + 16) * N_DIM + gn] = fmaf(s1, sc[gn], bi[gn]);
}

extern "C" void kernel_launch(void* const* d_in, const int* in_sizes, int n_in,
                              void* d_out, int out_size, void* d_ws, size_t ws_size,
                              hipStream_t stream) {
  const float*    x  = (const float*)d_in[0];     // f32 [32,8192]
  const uint32_t* bq = (const uint32_t*)d_in[1];  // int32 [8192,1024]
  const float*    sc = (const float*)d_in[2];     // f32 [8192]
  const float*    bi = (const float*)d_in[3];     // f32 [8192]
  float*          y  = (float*)d_out;             // f32 [32,8192]

  const size_t XP_BYTES = (size_t)M_DIM * K_DIM * 2;  // 512 KB f16
  if (ws_size >= XP_BYTES) {                          // constant -> graph-safe
    uint4* xp = (uint4*)d_ws;
    xprep_kernel<<<128, 256, 0, stream>>>(x, xp);
    qgemm_xp<<<N_DIM / 32, 1024, 0, stream>>>(bq, xp, sc, bi, y);
  } else {
    qgemm_direct<<<N_DIM / 32, 512, 0, stream>>>(bq, x, sc, bi, y);
  }
}

// Round 6
// 87.388 us; speedup vs baseline: 1.4315x; 1.0041x over previous
//
#include <hip/hip_runtime.h>
#include <cstdint>

// y[m][n] = sum_k x[m][k] * (q[n][k] * scale[n]) + bias[n]
// M=32, K=8192, N=8192; q = signed int4 nibbles packed 8 per int32.
// Harness dtype reality (verified round 4): fp16 tensors are FLOAT32 on
// device (inputs and output); b_packed is int32. ws_size ~268 MB.
#define M_DIM 32
#define K_DIM 8192
#define N_DIM 8192

typedef _Float16 f16x8 __attribute__((ext_vector_type(8)));
typedef _Float16 f16x2 __attribute__((ext_vector_type(2)));
typedef float    f32x4 __attribute__((ext_vector_type(4)));

__device__ __forceinline__ uint32_t u4e(uint4 v, int t) {
  return (t == 0) ? v.x : (t == 1) ? v.y : (t == 2) ? v.z : v.w;
}

// Magic-bias dequant: dword (8 nibbles) -> 8 exact f16 in [-8,7].
// t_s = ((w>>4s) & 0x000F000F) ^ 0x64086408 = f16x2 {1024+(n_s^8), 1024+(n_{s+4}^8)}
// minus 1032.0 -> {val(n_s), val(n_{s+4})} exactly (integers < 2048, exact f16).
// Fragment element j therefore holds nibble kp[j] = (j>>1) + (j&1)*4; xprep
// bakes the SAME permutation into the A layout, so the MFMA dot is exact.
// ~15 VALU/dword vs ~36 for shift-decode.
__device__ __forceinline__ f16x8 dq8(uint32_t w) {
  union { uint32_t u[4]; f16x8 v; } r;
  const uint32_t MASK  = 0x000F000Fu;
  const uint32_t MAGIC = 0x64086408u;                 // f16x2 {1032, 1032}
  const f16x2 magic = __builtin_bit_cast(f16x2, MAGIC);
#pragma unroll
  for (int s = 0; s < 4; ++s) {
    uint32_t t = ((w >> (4 * s)) & MASK) ^ MAGIC;
    f16x2 h = __builtin_bit_cast(f16x2, t) - magic;   // v_pk_add_f16 (neg)
    r.u[s] = __builtin_bit_cast(uint32_t, h);
  }
  return r.v;
}

// -------- x prep: f32 x[32][8192] -> f16 xp[g=k/8][m][8], nibble-pair perm --
// Element j of each 8-group = x[k = g*8 + (j>>1) + (j&1)*4]  (interleave lo/hi).
__global__ __launch_bounds__(256) void xprep_kernel(
    const float* __restrict__ x, uint4* __restrict__ xp) {
  const int T = blockIdx.x * 256 + threadIdx.x;  // 0..32767
  const int m = T >> 10;                         // 0..31
  const int g = T & 1023;                        // 0..1023
  const f32x4* p = (const f32x4*)(x + (size_t)m * K_DIM + (size_t)g * 8);
  f32x4 lo = p[0], hi = p[1];
  union { uint4 q; f16x8 v; } o;
#pragma unroll
  for (int s = 0; s < 4; ++s) {
    o.v[2 * s]     = (_Float16)lo[s];            // nibble-pair perm: {lo_s, hi_s}
    o.v[2 * s + 1] = (_Float16)hi[s];
  }
  xp[(size_t)g * 32 + m] = o.q;
}

// -------- main GEMM: 256 WGs x 1024 thr (16 waves) -------------------------
// WG = 32 cols (n) x 32 rows (m); 16 waves k-split (512 k each).
// All 8 B uint4 prefetched up front (whole WG HBM demand in flight at t=0);
// A ping-pong by t-group (4 uint4 live -> no VGPR spill at the 128 cap).
// k-scramble: slot (c,t,quad,j) takes k = (w*64+c*16+quad*4+t)*8 + kp[j]
// from BOTH operands — same bijection, exact dot product.
__global__ __launch_bounds__(1024, 4) void qgemm_xp(
    const uint32_t* __restrict__ bq,     // packed int4 [N, K/8]
    const uint4*    __restrict__ xp,     // f16 [1024][32][8] (perm'd)
    const float*    __restrict__ sc,     // f32 [8192]
    const float*    __restrict__ bi,     // f32 [8192]
    float*          __restrict__ out) {  // f32 [32, 8192]
  __shared__ float red[16][32][33];      // [wave][n][m], stride 33 (66 KB)

  const int tid  = threadIdx.x;
  const int w    = tid >> 6;             // wave 0..15 -> k0 = w*512
  const int lane = tid & 63;
  const int l16  = lane & 15;
  const int quad = lane >> 4;
  const int n0   = blockIdx.x << 5;      // 32 n per WG

  // B uint4 index: row*256 + w*16 + c*4 + quad; rows n0+l16, n0+l16+16
  const uint4* bq4 = (const uint4*)bq;
  const uint4* bp0 = bq4 + (size_t)(n0 + l16) * 256 + (w << 4) + quad;
  const uint4* bp1 = bp0 + (size_t)16 * 256;
  // A uint4 index: g*32 + m; g = w*64 + quad*4 + c*16 + t; m = l16 (+16)
  const uint4* ap  = xp + (size_t)(((w << 6) + (quad << 2)) * 32 + l16);

  // Prefetch ALL B: 4 chunks x 2 n-tiles = 8 outstanding HBM loads.
  uint4 b0[4], b1[4];
#pragma unroll
  for (int c = 0; c < 4; ++c) { b0[c] = bp0[c * 4]; b1[c] = bp1[c * 4]; }

  f32x4 acc00 = {0.f, 0.f, 0.f, 0.f};
  f32x4 acc01 = {0.f, 0.f, 0.f, 0.f};
  f32x4 acc10 = {0.f, 0.f, 0.f, 0.f};
  f32x4 acc11 = {0.f, 0.f, 0.f, 0.f};

  // A ping-pong over 16 t-groups; group g' -> uint4 offset ((g'>>2)*16+(g'&3))*32.
  uint4 a0c = ap[0], a1c = ap[16];       // group 0, both m-tiles
#pragma unroll
  for (int g = 0; g < 16; ++g) {
    const int gn  = (g + 1) & 15;        // last iter refetches group 0 (harmless)
    const int off = (((gn >> 2) * 16) + (gn & 3)) * 32;
    uint4 a0n = ap[off];
    uint4 a1n = ap[off + 16];

    const int c = g >> 2, t = g & 3;
    f16x8 fb0 = dq8(u4e(b0[c], t));
    f16x8 fb1 = dq8(u4e(b1[c], t));
    f16x8 fa0 = __builtin_bit_cast(f16x8, a0c);
    f16x8 fa1 = __builtin_bit_cast(f16x8, a1c);
    acc00 = __builtin_amdgcn_mfma_f32_16x16x32_f16(fa0, fb0, acc00, 0, 0, 0);
    acc01 = __builtin_amdgcn_mfma_f32_16x16x32_f16(fa1, fb0, acc01, 0, 0, 0);
    acc10 = __builtin_amdgcn_mfma_f32_16x16x32_f16(fa0, fb1, acc10, 0, 0, 0);
    acc11 = __builtin_amdgcn_mfma_f32_16x16x32_f16(fa1, fb1, acc11, 0, 0, 0);

    a0c = a0n; a1c = a1n;                // renamed away by full unroll
  }

  // C/D layout (verified round 4): n = lane&15, m = quad*4 + r.
#pragma unroll
  for (int r = 0; r < 4; ++r) {
    const int mr = (quad << 2) + r;
    red[w][l16][mr]           = acc00[r];
    red[w][l16][mr + 16]      = acc01[r];
    red[w][l16 + 16][mr]      = acc10[r];
    red[w][l16 + 16][mr + 16] = acc11[r];
  }

  __syncthreads();

  // 1024 threads = one output each: n = tid&31, m = tid>>5; stride-33 rows
  // make the 16-way read conflict-free across lanes.
  const int n = tid & 31;
  const int m = tid >> 5;
  float s = 0.f;
#pragma unroll
  for (int ww = 0; ww < 16; ++ww) s += red[ww][n][m];
  const int gn = n0 + n;
  out[(size_t)m * N_DIM + gn] = fmaf(s, sc[gn], bi[gn]);
}

// -------- fallback (tiny ws): round-4 known-good direct kernel -------------
__global__ __launch_bounds__(512) void qgemm_direct(
    const uint32_t* __restrict__ bq, const float* __restrict__ x,
    const float* __restrict__ sc, const float* __restrict__ bi,
    float* __restrict__ out) {
  __shared__ float red[8][32][40];
  const int tid  = threadIdx.x;
  const int w    = tid >> 6;
  const int lane = tid & 63;
  const int l16  = lane & 15;
  const int quad = lane >> 4;
  const int n0   = blockIdx.x << 5;

  const uint4* bq4 = (const uint4*)bq;
  const uint4* bp0 = bq4 + (size_t)(n0 + l16) * 256 + (w << 5) + quad;
  const uint4* bp1 = bp0 + (size_t)16 * 256;
  const float* ap0 = x + (size_t)l16 * K_DIM + (w << 10) + (quad << 5);
  const float* ap1 = ap0 + (size_t)16 * K_DIM;

  f32x4 acc00 = {0.f,0.f,0.f,0.f}, acc01 = {0.f,0.f,0.f,0.f};
  f32x4 acc10 = {0.f,0.f,0.f,0.f}, acc11 = {0.f,0.f,0.f,0.f};
#pragma unroll
  for (int c = 0; c < 8; ++c) {
    const uint4 wb0 = bp0[c * 4];
    const uint4 wb1 = bp1[c * 4];
#pragma unroll
    for (int t = 0; t < 4; ++t) {
      const float* a0 = ap0 + c * 128 + t * 8;
      const float* a1 = ap1 + c * 128 + t * 8;
      f32x4 l0 = *(const f32x4*)a0, h0 = *(const f32x4*)(a0 + 4);
      f32x4 l1 = *(const f32x4*)a1, h1 = *(const f32x4*)(a1 + 4);
      f16x8 fa0, fa1;
#pragma unroll
      for (int s = 0; s < 4; ++s) {
        fa0[2*s] = (_Float16)l0[s]; fa0[2*s+1] = (_Float16)h0[s];
        fa1[2*s] = (_Float16)l1[s]; fa1[2*s+1] = (_Float16)h1[s];
      }
      f16x8 fb0 = dq8(u4e(wb0, t));
      f16x8 fb1 = dq8(u4e(wb1, t));
      acc00 = __builtin_amdgcn_mfma_f32_16x16x32_f16(fa0, fb0, acc00, 0, 0, 0);
      acc01 = __builtin_amdgcn_mfma_f32_16x16x32_f16(fa1, fb0, acc01, 0, 0, 0);
      acc10 = __builtin_amdgcn_mfma_f32_16x16x32_f16(fa0, fb1, acc10, 0, 0, 0);
      acc11 = __builtin_amdgcn_mfma_f32_16x16x32_f16(fa1, fb1, acc11, 0, 0, 0);
    }
  }
#pragma unroll
  for (int r = 0; r < 4; ++r) {
    const int mr = (quad << 2) + r;
    red[w][l16][mr]           = acc00[r];
    red[w][l16][mr + 16]      = acc01[r];
    red[w][l16 + 16][mr]      = acc10[r];
    red[w][l16 + 16][mr + 16] = acc11[r];
  }
  __syncthreads();
  const int n  = tid & 31;
  const int mh = tid >> 5;
  float s0 = 0.f, s1 = 0.f;
#pragma unroll
  for (int ww = 0; ww < 8; ++ww) { s0 += red[ww][n][mh]; s1 += red[ww][n][mh+16]; }
  const int gn = n0 + n;
  out[(size_t)mh * N_DIM + gn]        = fmaf(s0, sc[gn], bi[gn]);
  out[(size_t)(mh + 16) * N_DIM + gn] = fmaf(s1, sc[gn], bi[gn]);
}

extern "C" void kernel_launch(void* const* d_in, const int* in_sizes, int n_in,
                              void* d_out, int out_size, void* d_ws, size_t ws_size,
                              hipStream_t stream) {
  const float*    x  = (const float*)d_in[0];     // f32 [32,8192]
  const uint32_t* bq = (const uint32_t*)d_in[1];  // int32 [8192,1024]
  const float*    sc = (const float*)d_in[2];     // f32 [8192]
  const float*    bi = (const float*)d_in[3];     // f32 [8192]
  float*          y  = (float*)d_out;             // f32 [32,8192]

  const size_t XP_BYTES = (size_t)M_DIM * K_DIM * 2;  // 512 KB f16
  if (ws_size >= XP_BYTES) {                          // constant -> graph-safe
    uint4* xp = (uint4*)d_ws;
    xprep_kernel<<<128, 256, 0, stream>>>(x, xp);
    qgemm_xp<<<N_DIM / 32, 1024, 0, stream>>>(bq, xp, sc, bi, y);
  } else {
    qgemm_direct<<<N_DIM / 32, 512, 0, stream>>>(bq, x, sc, bi, y);
  }
}